// Round 7
// baseline (564854.883 us; speedup 1.0000x reference)
//
#include <hip/hip_runtime.h>

#define SEQ  8192
#define HID  1024
#define NBLK 32
#define WPB  16            // waves per block
#define TPB  1024
#define KCH  16            // h index = lane + 64*k
#define SLOT_WORDS (2 * HID)

__device__ __forceinline__ float sigmoidf_fast(float a) {
    return 1.0f / (1.0f + __expf(-a));
}
__device__ __forceinline__ float tanhf_fast(float a) {
    float t = fabsf(a);
    float e = __expf(-2.0f * t);
    float r = (1.0f - e) / (1.0f + e);
    return copysignf(r, a);
}

// 6 raw dot-products (rows r0,z0,n0,r1,z1,n1) of x against W_ih rows, reduced wave-wide.
__device__ __forceinline__ void dot6(const float* __restrict__ x,
                                     const float* __restrict__ pr0, const float* __restrict__ pz0,
                                     const float* __restrict__ pn0, const float* __restrict__ pr1,
                                     const float* __restrict__ pz1, const float* __restrict__ pn1,
                                     int lane,
                                     float& dr0, float& dz0, float& dn0,
                                     float& dr1, float& dz1, float& dn1)
{
    float ar0 = 0.f, az0 = 0.f, an0 = 0.f, ar1 = 0.f, az1 = 0.f, an1 = 0.f;
#pragma unroll
    for (int k = 0; k < KCH; ++k) {
        const int i = lane + 64 * k;
        float xv = x[i];
        ar0 = fmaf(pr0[i], xv, ar0);
        az0 = fmaf(pz0[i], xv, az0);
        an0 = fmaf(pn0[i], xv, an0);
        ar1 = fmaf(pr1[i], xv, ar1);
        az1 = fmaf(pz1[i], xv, az1);
        an1 = fmaf(pn1[i], xv, an1);
    }
#pragma unroll
    for (int m = 32; m >= 1; m >>= 1) {
        ar0 += __shfl_xor(ar0, m, 64);
        az0 += __shfl_xor(az0, m, 64);
        an0 += __shfl_xor(an0, m, 64);
        ar1 += __shfl_xor(ar1, m, 64);
        az1 += __shfl_xor(az1, m, 64);
        an1 += __shfl_xor(an1, m, 64);
    }
    dr0 = ar0; dz0 = az0; dn0 = an0; dr1 = ar1; dz1 = az1; dn1 = an1;
}

__global__ __launch_bounds__(TPB) void gru_persistent(
    const float* __restrict__ inp,   // [SEQ, HID]
    const float* __restrict__ Wih,   // [3*HID, HID]
    const float* __restrict__ Whh,   // [3*HID, HID]
    const float* __restrict__ bih,   // [3*HID]
    const float* __restrict__ bhh,   // [3*HID]
    float* __restrict__ out,         // [SEQ, HID]
    unsigned long long* __restrict__ slots)  // [2][HID] tagged words
{
    __shared__ float hbuf[HID];      // h_{t-1}, refilled by wave0 each step
    __shared__ float xh[2][8];       // wave0's raw x-dots, written by wave1, parity-buffered
    const int tid  = threadIdx.x;
    const int wave = tid >> 6;
    const int lane = tid & 63;
    const int j0   = blockIdx.x * (WPB * 2) + wave * 2;   // this wave's rows: j0, j0+1

    // ---- persistent W_hh rows (6 rows' worth) in VGPRs: 96 regs/thread ----
    float w0r[KCH], w0z[KCH], w0n[KCH], w1r[KCH], w1z[KCH], w1n[KCH];
    {
        const float* p0r = Whh + (size_t)j0 * HID;
        const float* p0z = Whh + (size_t)(HID + j0) * HID;
        const float* p0n = Whh + (size_t)(2 * HID + j0) * HID;
#pragma unroll
        for (int k = 0; k < KCH; ++k) {
            const int i = lane + 64 * k;
            w0r[k] = p0r[i];          w1r[k] = p0r[i + HID];
            w0z[k] = p0z[i];          w1z[k] = p0z[i + HID];
            w0n[k] = p0n[i];          w1n[k] = p0n[i + HID];
        }
    }
    // combined biases: r/z gates always see bih+bhh summed; n gate needs them split
    const float br0  = bih[j0]           + bhh[j0];
    const float bz0  = bih[HID + j0]     + bhh[HID + j0];
    const float bxn0 = bih[2 * HID + j0];
    const float bhn0 = bhh[2 * HID + j0];
    const float br1  = bih[j0 + 1]       + bhh[j0 + 1];
    const float bz1  = bih[HID + j0 + 1] + bhh[HID + j0 + 1];
    const float bxn1 = bih[2 * HID + j0 + 1];
    const float bhn1 = bhh[2 * HID + j0 + 1];

    // W_ih row pointers for own rows (wave-uniform -> SGPRs)
    const float* U0r = Wih + (size_t)j0 * HID;
    const float* U0z = Wih + (size_t)(HID + j0) * HID;
    const float* U0n = Wih + (size_t)(2 * HID + j0) * HID;

    // ---- prologue: x-dots for t=1. Waves 1..15 compute their own; wave1 also
    //      computes wave0's (rows j0-2, j0-1) and parks them in xh[1]. Wave0 idles. ----
    float x0r = 0.f, x0z = 0.f, x0n = 0.f, x1r = 0.f, x1z = 0.f, x1n = 0.f;
    if (wave != 0) {
        dot6(inp, U0r, U0z, U0n, U0r + HID, U0z + HID, U0n + HID, lane,
             x0r, x0z, x0n, x1r, x1z, x1n);
        if (wave == 1) {
            float pr0, pz0, pn0, pr1, pz1, pn1;
            dot6(inp, U0r - 2 * (size_t)HID, U0z - 2 * (size_t)HID, U0n - 2 * (size_t)HID,
                 U0r - HID, U0z - HID, U0n - HID, lane, pr0, pz0, pn0, pr1, pz1, pn1);
            if (lane == 0) {
                xh[1][0] = pr0; xh[1][1] = pz0; xh[1][2] = pn0;
                xh[1][3] = pr1; xh[1][4] = pz1; xh[1][5] = pn1;
            }
        }
    }

    for (int t = 1; t <= SEQ; ++t) {
        // ---- wave0: merged poll+fetch — the detection load IS the data load ----
        if (wave == 0) {
            const unsigned long long* rd = slots + ((t - 1) & 1) * HID;
            const unsigned expect = (unsigned)(t - 1);
            for (;;) {
                float v[KCH];
                bool ok = true;
#pragma unroll
                for (int k = 0; k < KCH; ++k) {
                    unsigned long long wv = __hip_atomic_load(
                        rd + lane + 64 * k, __ATOMIC_RELAXED, __HIP_MEMORY_SCOPE_AGENT);
                    ok &= ((unsigned)(wv >> 32) == expect);
                    v[k] = __uint_as_float((unsigned)(wv & 0xffffffffu));
                }
                if (__all(ok)) {
#pragma unroll
                    for (int k = 0; k < KCH; ++k) hbuf[lane + 64 * k] = v[k];
                    break;
                }
                __builtin_amdgcn_s_sleep(1);
            }
        }
        __syncthreads();   // the ONE barrier per step

        // ---- h-side matvec for both rows from persistent VGPR weights ----
        float a0r = 0.f, a0z = 0.f, a0n = 0.f, a1r = 0.f, a1z = 0.f, a1n = 0.f;
#pragma unroll
        for (int k = 0; k < KCH; ++k) {
            float hv = hbuf[lane + 64 * k];
            a0r = fmaf(w0r[k], hv, a0r);
            a0z = fmaf(w0z[k], hv, a0z);
            a0n = fmaf(w0n[k], hv, a0n);
            a1r = fmaf(w1r[k], hv, a1r);
            a1z = fmaf(w1z[k], hv, a1z);
            a1n = fmaf(w1n[k], hv, a1n);
        }
#pragma unroll
        for (int m = 32; m >= 1; m >>= 1) {
            a0r += __shfl_xor(a0r, m, 64);
            a0z += __shfl_xor(a0z, m, 64);
            a0n += __shfl_xor(a0n, m, 64);
            a1r += __shfl_xor(a1r, m, 64);
            a1z += __shfl_xor(a1z, m, 64);
            a1n += __shfl_xor(a1n, m, 64);
        }

        // x-dots: wave0 takes wave1's proxy results from LDS
        float xr0, xz0, xn0, xr1, xz1, xn1;
        if (wave == 0) {
            const float* xp = xh[t & 1];
            xr0 = xp[0]; xz0 = xp[1]; xn0 = xp[2];
            xr1 = xp[3]; xz1 = xp[4]; xn1 = xp[5];
        } else {
            xr0 = x0r; xz0 = x0z; xn0 = x0n;
            xr1 = x1r; xz1 = x1z; xn1 = x1n;
        }

        const float hp0 = hbuf[j0], hp1 = hbuf[j0 + 1];
        const float r0 = sigmoidf_fast(xr0 + a0r + br0);
        const float z0 = sigmoidf_fast(xz0 + a0z + bz0);
        const float n0 = tanhf_fast(xn0 + bxn0 + r0 * (a0n + bhn0));
        const float h0n = (1.0f - z0) * n0 + z0 * hp0;
        const float r1 = sigmoidf_fast(xr1 + a1r + br1);
        const float z1 = sigmoidf_fast(xz1 + a1z + bz1);
        const float n1 = tanhf_fast(xn1 + bxn1 + r1 * (a1n + bhn1));
        const float h1n = (1.0f - z1) * n1 + z1 * hp1;

        const float hpub = (lane & 1) ? h1n : h0n;
        if (lane < 2) {
            if (t < SEQ) {   // publish FIRST — the only thing other blocks wait on
                unsigned long long pub = ((unsigned long long)(unsigned)t << 32)
                                       | (unsigned long long)__float_as_uint(hpub);
                __hip_atomic_store(slots + (t & 1) * HID + j0 + lane, pub,
                                   __ATOMIC_RELAXED, __HIP_MEMORY_SCOPE_AGENT);
            }
            __builtin_nontemporal_store(hpub, out + (size_t)(t - 1) * HID + j0 + lane);
        }

        // ---- tail: x-dots for t+1, fully off wave0's path (hides under fabric RT) ----
        if (t < SEQ) {
            const float* x = inp + (size_t)t * HID;
            if (wave != 0) {
                dot6(x, U0r, U0z, U0n, U0r + HID, U0z + HID, U0n + HID, lane,
                     x0r, x0z, x0n, x1r, x1z, x1n);
                if (wave == 1) {
                    float pr0, pz0, pn0, pr1, pz1, pn1;
                    dot6(x, U0r - 2 * (size_t)HID, U0z - 2 * (size_t)HID,
                         U0n - 2 * (size_t)HID, U0r - HID, U0z - HID, U0n - HID,
                         lane, pr0, pz0, pn0, pr1, pz1, pn1);
                    if (lane == 0) {
                        float* xp = xh[(t + 1) & 1];
                        xp[0] = pr0; xp[1] = pz0; xp[2] = pn0;
                        xp[3] = pr1; xp[4] = pz1; xp[5] = pn1;
                    }
                }
            }
        }
        // no trailing barrier needed: next step's poll (wave0) and the barrier after it
        // order xh/hbuf reuse; hbuf overwrite is gated by the poll itself (all blocks
        // published t => all waves finished reading hbuf for step t's compute).
    }
}

extern "C" void kernel_launch(void* const* d_in, const int* in_sizes, int n_in,
                              void* d_out, int out_size, void* d_ws, size_t ws_size,
                              hipStream_t stream) {
    const float* inp = (const float*)d_in[0];
    const float* Wih = (const float*)d_in[1];
    const float* Whh = (const float*)d_in[2];
    const float* bih = (const float*)d_in[3];
    const float* bhh = (const float*)d_in[4];
    float* out = (float*)d_out;
    unsigned long long* slots = (unsigned long long*)d_ws;

    // zero both parity planes: tag 0 / value 0.0f == h_0 = 0 (t=1 poll passes instantly)
    hipMemsetAsync(slots, 0, SLOT_WORDS * sizeof(unsigned long long), stream);

    gru_persistent<<<dim3(NBLK), dim3(TPB), 0, stream>>>(
        inp, Wih, Whh, bih, bhh, out, slots);
}

// Round 8
// 99987.781 us; speedup vs baseline: 5.6492x; 5.6492x over previous
//
#include <hip/hip_runtime.h>

#define SEQ  8192
#define HID  1024
#define NBLK 64
#define WPB  16            // waves per block
#define TPB  1024
#define KCH  16            // h/x index = lane + 64*k
#define SLOT_WORDS (2 * HID)

__device__ __forceinline__ float sigmoidf_fast(float a) {
    return 1.0f / (1.0f + __expf(-a));
}
__device__ __forceinline__ float tanhf_fast(float a) {
    float t = fabsf(a);
    float e = __expf(-2.0f * t);
    float r = (1.0f - e) / (1.0f + e);
    return copysignf(r, a);
}

// 3 raw dot-products (rows r,z,n of W_ih) against x, reduced wave-wide. No bias.
__device__ __forceinline__ void dot3(const float* __restrict__ x,
                                     const float* __restrict__ pr,
                                     const float* __restrict__ pz,
                                     const float* __restrict__ pn,
                                     int lane, float& dr, float& dz, float& dn)
{
    float ar = 0.f, az = 0.f, an = 0.f;
#pragma unroll
    for (int k = 0; k < KCH; ++k) {
        const int i = lane + 64 * k;
        float xv = x[i];
        ar = fmaf(pr[i], xv, ar);
        az = fmaf(pz[i], xv, az);
        an = fmaf(pn[i], xv, an);
    }
#pragma unroll
    for (int m = 32; m >= 1; m >>= 1) {
        ar += __shfl_xor(ar, m, 64);
        az += __shfl_xor(az, m, 64);
        an += __shfl_xor(an, m, 64);
    }
    dr = ar; dz = az; dn = an;
}

__global__ __launch_bounds__(TPB, 4) void gru_persistent(   // ",4" is LOAD-BEARING:
    const float* __restrict__ inp,   // without it the compiler demotes the weight
    const float* __restrict__ Wih,   // arrays and re-fetches W_hh every step (R7:
    const float* __restrict__ Whh,   // FETCH_SIZE 91 GB, 565 ms)
    const float* __restrict__ bih,
    const float* __restrict__ bhh,
    float* __restrict__ out,         // [SEQ, HID]
    unsigned long long* __restrict__ slots)  // [2][HID] (step_tag<<32)|f32bits
{
    __shared__ float hbuf[HID];      // h_{t-1}, refilled by wave0 each step
    __shared__ float xh[2][4];       // wave0's raw x-dots (r,z,n), written by wave1
    const int tid  = threadIdx.x;
    const int wave = tid >> 6;
    const int lane = tid & 63;
    const int j    = blockIdx.x * WPB + wave;   // this wave's output row

    // ---- persistent W_hh rows (j, HID+j, 2*HID+j) in VGPRs: 48 regs/thread ----
    float wr[KCH], wz[KCH], wn[KCH];
    {
        const float* Wr = Whh + (size_t)j * HID;
        const float* Wz = Whh + (size_t)(HID + j) * HID;
        const float* Wn = Whh + (size_t)(2 * HID + j) * HID;
#pragma unroll
        for (int k = 0; k < KCH; ++k) {
            wr[k] = Wr[lane + 64 * k];
            wz[k] = Wz[lane + 64 * k];
            wn[k] = Wn[lane + 64 * k];
        }
    }
    // r/z gates see bih+bhh summed; n gate needs the split (r multiplies bhh_n)
    const float bra  = bih[j]           + bhh[j];
    const float bza  = bih[HID + j]     + bhh[HID + j];
    const float bxn  = bih[2 * HID + j];
    const float bhn  = bhh[2 * HID + j];

    const float* Ur = Wih + (size_t)j * HID;    // wave-uniform row pointers
    const float* Uz = Wih + (size_t)(HID + j) * HID;
    const float* Un = Wih + (size_t)(2 * HID + j) * HID;

    // ---- prologue x-dots for t=1: waves 1..15 their own; wave1 also proxies
    //      wave0's row (j-1 relative to wave1 => pointers minus HID). Wave0: none.
    float xdr = 0.f, xdz = 0.f, xdn = 0.f;
    if (wave != 0) {
        dot3(inp, Ur, Uz, Un, lane, xdr, xdz, xdn);
        if (wave == 1) {
            float pr, pz, pn;
            dot3(inp, Ur - HID, Uz - HID, Un - HID, lane, pr, pz, pn);
            if (lane == 0) { xh[1][0] = pr; xh[1][1] = pz; xh[1][2] = pn; }
        }
    }

    for (int t = 1; t <= SEQ; ++t) {
        // ---- wave0: merged poll+fetch, per-word done-mask + backoff ----
        if (wave == 0) {
            const unsigned long long* rd = slots + ((t - 1) & 1) * HID;
            const unsigned expect = (unsigned)(t - 1);
            float v[KCH];
            bool pend[KCH];
#pragma unroll
            for (int k = 0; k < KCH; ++k) pend[k] = true;
            int iter = 0;
            for (;;) {
                bool anypend = false;
#pragma unroll
                for (int k = 0; k < KCH; ++k) {
                    if (pend[k]) {   // exec-masked: landed words are never re-read
                        unsigned long long wv = __hip_atomic_load(
                            rd + lane + 64 * k, __ATOMIC_RELAXED, __HIP_MEMORY_SCOPE_AGENT);
                        if ((unsigned)(wv >> 32) == expect) {
                            v[k] = __uint_as_float((unsigned)(wv & 0xffffffffu));
                            pend[k] = false;
                        } else {
                            anypend = true;
                        }
                    }
                }
                if (__all(!anypend)) break;
                if (iter < 2) __builtin_amdgcn_s_sleep(1);   // fast path: land imminently
                else          __builtin_amdgcn_s_sleep(8);   // backoff: stop hammering lines
                ++iter;
            }
#pragma unroll
            for (int k = 0; k < KCH; ++k) hbuf[lane + 64 * k] = v[k];
        }
        __syncthreads();   // the ONE barrier per step

        // ---- h-side matvec from persistent VGPR weights ----
        float hr = 0.f, hz = 0.f, hn = 0.f;
#pragma unroll
        for (int k = 0; k < KCH; ++k) {
            float hv = hbuf[lane + 64 * k];
            hr = fmaf(wr[k], hv, hr);
            hz = fmaf(wz[k], hv, hz);
            hn = fmaf(wn[k], hv, hn);
        }
#pragma unroll
        for (int m = 32; m >= 1; m >>= 1) {
            hr += __shfl_xor(hr, m, 64);
            hz += __shfl_xor(hz, m, 64);
            hn += __shfl_xor(hn, m, 64);
        }

        // wave0 takes its x-dots from wave1's proxy (parity-buffered LDS)
        float xr = xdr, xz = xdz, xn = xdn;
        if (wave == 0) {
            const float* xp = xh[t & 1];
            xr = xp[0]; xz = xp[1]; xn = xp[2];
        }

        const float hprev = hbuf[j];
        const float r = sigmoidf_fast(xr + hr + bra);
        const float z = sigmoidf_fast(xz + hz + bza);
        const float n = tanhf_fast(xn + bxn + r * (hn + bhn));
        const float hnew = (1.0f - z) * n + z * hprev;

        if (lane == 0) {
            if (t < SEQ) {   // publish FIRST — the only thing other blocks wait on
                unsigned long long pub = ((unsigned long long)(unsigned)t << 32)
                                       | (unsigned long long)__float_as_uint(hnew);
                __hip_atomic_store(slots + (t & 1) * HID + j, pub,
                                   __ATOMIC_RELAXED, __HIP_MEMORY_SCOPE_AGENT);
            }
            __builtin_nontemporal_store(hnew, out + (size_t)(t - 1) * HID + j);
        }

        // ---- tail: x-dots for t+1 — NEVER on wave0 (kept off the consumer path);
        //      wave1's extra dot3 hides under the publish->detect fabric gap ----
        if (t < SEQ && wave != 0) {
            const float* x = inp + (size_t)t * HID;
            dot3(x, Ur, Uz, Un, lane, xdr, xdz, xdn);
            if (wave == 1) {
                float pr, pz, pn;
                dot3(x, Ur - HID, Uz - HID, Un - HID, lane, pr, pz, pn);
                if (lane == 0) {
                    float* xp = xh[(t + 1) & 1];
                    xp[0] = pr; xp[1] = pz; xp[2] = pn;
                }
            }
        }
        // no trailing barrier: hbuf overwrite is gated by the next poll (all blocks
        // published t => every wave finished reading hbuf); xh is parity-disjoint.
    }
}

extern "C" void kernel_launch(void* const* d_in, const int* in_sizes, int n_in,
                              void* d_out, int out_size, void* d_ws, size_t ws_size,
                              hipStream_t stream) {
    const float* inp = (const float*)d_in[0];
    const float* Wih = (const float*)d_in[1];
    const float* Whh = (const float*)d_in[2];
    const float* bih = (const float*)d_in[3];
    const float* bhh = (const float*)d_in[4];
    float* out = (float*)d_out;
    unsigned long long* slots = (unsigned long long*)d_ws;

    // zero both parity planes: tag 0 / value 0.0f == h_0 = 0 (t=1 poll passes instantly)
    hipMemsetAsync(slots, 0, SLOT_WORDS * sizeof(unsigned long long), stream);

    gru_persistent<<<dim3(NBLK), dim3(TPB), 0, stream>>>(
        inp, Wih, Whh, bih, bhh, out, slots);
}